// Round 10
// baseline (12128.658 us; speedup 1.0000x reference)
//
#include <hip/hip_runtime.h>

#define NN 512
#define DD 32
#define TT 8192

typedef float v4f __attribute__((ext_vector_type(4)));
typedef float v2f __attribute__((ext_vector_type(2)));
typedef float v16f __attribute__((ext_vector_type(16)));
typedef __attribute__((address_space(3))) float lds_f;

constexpr float F_OMEGA = 10.0f;
constexpr float F_DT = 1e-3f;
constexpr float F_TWO_PI = 6.28318530717958647692f;
constexpr float F_INV_TWO_PI = 0.15915494309189533577f;

__device__ __forceinline__ void barrier_lgkm() {
    asm volatile("s_waitcnt lgkmcnt(0)\n\ts_barrier" ::: "memory");
}

#define DSR128(dst, addr, off) \
    asm volatile("ds_read_b128 %0, %1 offset:" #off : "=v"(dst) : "v"(addr))

#define SL1(dst, ptr) \
    asm volatile("s_load_dword %0, %1, 0x0" : "=s"(dst) : "s"(ptr))

#define DPP_ADD(x, ctrl, rmask)                                                 \
    {                                                                           \
        int _t = __builtin_amdgcn_update_dpp(0, __float_as_int(x),              \
                                             (ctrl), (rmask), 0xf, true);       \
        (x) += __int_as_float(_t);                                              \
    }

__device__ __forceinline__ float wave_reduce_to_lane63(float x) {
    DPP_ADD(x, 0xB1, 0xf);   // + xor1
    DPP_ADD(x, 0x4E, 0xf);   // + xor2
    DPP_ADD(x, 0x141, 0xf);  // + xor4
    DPP_ADD(x, 0x140, 0xf);  // + xor8
    DPP_ADD(x, 0x142, 0xa);  // row_bcast15
    DPP_ADD(x, 0x143, 0xc);  // row_bcast31
    return x;                // lane 63 = full wave sum
}

// ---- register map (physical pins) ----
// W:    wr pairs v[64+2k],  wi pairs v[96+2k]    (v64..v127)
// bufA: xr pairs v[128+2k], xi pairs v[160+2k]   (v128..v191)  x(even t)
// bufB: xr pairs v[192+2k], xi pairs v[224+2k]   (v192..v255)  x(odd t)
// Pool v0..v63. x loads are uniform-address (all lanes same addr -> one L2
// transaction, value broadcast into every lane) so VALU ops are VGPRxVGPR.

#define MV_M(acc, a0, a1, b0, b1) \
    "v_pk_mul_f32 %[" #acc "], v[" #a0 ":" #a1 "], v[" #b0 ":" #b1 "]\n\t"
#define MV_F(acc, a0, a1, b0, b1) \
    "v_pk_fma_f32 %[" #acc "], v[" #a0 ":" #a1 "], v[" #b0 ":" #b1 "], %[" #acc "]\n\t"

// One W-update pair: scr = g2*x ; w = w*m1 + scr (same 2 ops/order as R6)
#define WU(w0, w1, x0, x1, SC) \
    "v_pk_mul_f32 %[" #SC "], %[g2], v[" #x0 ":" #x1 "]\n\t" \
    "v_pk_fma_f32 v[" #w0 ":" #w1 "], v[" #w0 ":" #w1 "], %[m1], %[" #SC "]\n\t"

__global__ __launch_bounds__(512, 2) void deerskin(
    const float* __restrict__ Xr, const float* __restrict__ Xi,
    const float* __restrict__ Tg,
    const float* __restrict__ W0r, const float* __restrict__ W0i,
    const float* __restrict__ Phi0, const float* __restrict__ Beta0,
    float* __restrict__ outs, float* __restrict__ betas, float* __restrict__ gammas)
{
    __shared__ __align__(16) float sP[16];

    const int n = threadIdx.x;
    const int lane = n & 63;
    const int wid = n >> 6;

    // ---- W pinned to v[64:127] ----
    v16f wrA, wrB, wiA, wiB;
    {
        const v16f* r = (const v16f*)(W0r + n * DD);
        const v16f* i = (const v16f*)(W0i + n * DD);
        v16f t0 = r[0], t1 = r[1], t2 = i[0], t3 = i[1];
        asm volatile("" : "={v[64:79]}"(wrA) : "0"(t0));
        asm volatile("" : "={v[80:95]}"(wrB) : "0"(t1));
        asm volatile("" : "={v[96:111]}"(wiA) : "0"(t2));
        asm volatile("" : "={v[112:127]}"(wiB) : "0"(t3));
    }

    float phi = Phi0[n];
    float beta = Beta0[n];
    float lt = 0.0f;
    float err = 0.0f;
    const float a_sB = 1.0f - __expf(-F_DT / 0.03f);  // step-invariant
    int vzero = 0;

    v16f axr0, axr1, axi0, axi1;   // bufA (pinned v128..191)
    v16f bxr0, bxr1, bxi0, bxi1;   // bufB (pinned v192..255)
    float tgA, tgB;                // carried SGPR targets
    v2f wuscr0, wuscr1;

#define LOADX_A(PXR, PXI) \
    asm volatile( \
        "global_load_dwordx4 v[128:131], %[vz], %[bxr]\n\t" \
        "global_load_dwordx4 v[132:135], %[vz], %[bxr] offset:16\n\t" \
        "global_load_dwordx4 v[136:139], %[vz], %[bxr] offset:32\n\t" \
        "global_load_dwordx4 v[140:143], %[vz], %[bxr] offset:48\n\t" \
        "global_load_dwordx4 v[144:147], %[vz], %[bxr] offset:64\n\t" \
        "global_load_dwordx4 v[148:151], %[vz], %[bxr] offset:80\n\t" \
        "global_load_dwordx4 v[152:155], %[vz], %[bxr] offset:96\n\t" \
        "global_load_dwordx4 v[156:159], %[vz], %[bxr] offset:112\n\t" \
        "global_load_dwordx4 v[160:163], %[vz], %[bxi]\n\t" \
        "global_load_dwordx4 v[164:167], %[vz], %[bxi] offset:16\n\t" \
        "global_load_dwordx4 v[168:171], %[vz], %[bxi] offset:32\n\t" \
        "global_load_dwordx4 v[172:175], %[vz], %[bxi] offset:48\n\t" \
        "global_load_dwordx4 v[176:179], %[vz], %[bxi] offset:64\n\t" \
        "global_load_dwordx4 v[180:183], %[vz], %[bxi] offset:80\n\t" \
        "global_load_dwordx4 v[184:187], %[vz], %[bxi] offset:96\n\t" \
        "global_load_dwordx4 v[188:191], %[vz], %[bxi] offset:112" \
        : "={v[128:143]}"(axr0), "={v[144:159]}"(axr1), \
          "={v[160:175]}"(axi0), "={v[176:191]}"(axi1) \
        : [vz]"v"(vzero), [bxr]"s"(PXR), [bxi]"s"(PXI) \
        : "memory")

#define LOADX_B(PXR, PXI) \
    asm volatile( \
        "global_load_dwordx4 v[192:195], %[vz], %[bxr]\n\t" \
        "global_load_dwordx4 v[196:199], %[vz], %[bxr] offset:16\n\t" \
        "global_load_dwordx4 v[200:203], %[vz], %[bxr] offset:32\n\t" \
        "global_load_dwordx4 v[204:207], %[vz], %[bxr] offset:48\n\t" \
        "global_load_dwordx4 v[208:211], %[vz], %[bxr] offset:64\n\t" \
        "global_load_dwordx4 v[212:215], %[vz], %[bxr] offset:80\n\t" \
        "global_load_dwordx4 v[216:219], %[vz], %[bxr] offset:96\n\t" \
        "global_load_dwordx4 v[220:223], %[vz], %[bxr] offset:112\n\t" \
        "global_load_dwordx4 v[224:227], %[vz], %[bxi]\n\t" \
        "global_load_dwordx4 v[228:231], %[vz], %[bxi] offset:16\n\t" \
        "global_load_dwordx4 v[232:235], %[vz], %[bxi] offset:32\n\t" \
        "global_load_dwordx4 v[236:239], %[vz], %[bxi] offset:48\n\t" \
        "global_load_dwordx4 v[240:243], %[vz], %[bxi] offset:64\n\t" \
        "global_load_dwordx4 v[244:247], %[vz], %[bxi] offset:80\n\t" \
        "global_load_dwordx4 v[248:251], %[vz], %[bxi] offset:96\n\t" \
        "global_load_dwordx4 v[252:255], %[vz], %[bxi] offset:112" \
        : "={v[192:207]}"(bxr0), "={v[208:223]}"(bxr1), \
          "={v[224:239]}"(bxi0), "={v[240:255]}"(bxi1) \
        : [vz]"v"(vzero), [bxr]"s"(PXR), [bxi]"s"(PXI) \
        : "memory")

    // Matvec: 8 chains, per-chain accumulation order identical to R6.
#define MATVEC_A() \
    asm volatile( \
        MV_M(arr0,64,65,128,129)   MV_M(arr1,66,67,130,131) \
        MV_M(air0,96,97,128,129)   MV_M(air1,98,99,130,131) \
        MV_F(arr0,68,69,132,133)   MV_F(arr1,70,71,134,135) \
        MV_F(air0,100,101,132,133) MV_F(air1,102,103,134,135) \
        MV_F(arr0,72,73,136,137)   MV_F(arr1,74,75,138,139) \
        MV_F(air0,104,105,136,137) MV_F(air1,106,107,138,139) \
        MV_F(arr0,76,77,140,141)   MV_F(arr1,78,79,142,143) \
        MV_F(air0,108,109,140,141) MV_F(air1,110,111,142,143) \
        MV_F(arr0,80,81,144,145)   MV_F(arr1,82,83,146,147) \
        MV_F(air0,112,113,144,145) MV_F(air1,114,115,146,147) \
        MV_F(arr0,84,85,148,149)   MV_F(arr1,86,87,150,151) \
        MV_F(air0,116,117,148,149) MV_F(air1,118,119,150,151) \
        MV_F(arr0,88,89,152,153)   MV_F(arr1,90,91,154,155) \
        MV_F(air0,120,121,152,153) MV_F(air1,122,123,154,155) \
        MV_F(arr0,92,93,156,157)   MV_F(arr1,94,95,158,159) \
        MV_F(air0,124,125,156,157) MV_F(air1,126,127,158,159) \
        MV_M(aii0,96,97,160,161)   MV_M(aii1,98,99,162,163) \
        MV_M(ari0,64,65,160,161)   MV_M(ari1,66,67,162,163) \
        MV_F(aii0,100,101,164,165) MV_F(aii1,102,103,166,167) \
        MV_F(ari0,68,69,164,165)   MV_F(ari1,70,71,166,167) \
        MV_F(aii0,104,105,168,169) MV_F(aii1,106,107,170,171) \
        MV_F(ari0,72,73,168,169)   MV_F(ari1,74,75,170,171) \
        MV_F(aii0,108,109,172,173) MV_F(aii1,110,111,174,175) \
        MV_F(ari0,76,77,172,173)   MV_F(ari1,78,79,174,175) \
        MV_F(aii0,112,113,176,177) MV_F(aii1,114,115,178,179) \
        MV_F(ari0,80,81,176,177)   MV_F(ari1,82,83,178,179) \
        MV_F(aii0,116,117,180,181) MV_F(aii1,118,119,182,183) \
        MV_F(ari0,84,85,180,181)   MV_F(ari1,86,87,182,183) \
        MV_F(aii0,120,121,184,185) MV_F(aii1,122,123,186,187) \
        MV_F(ari0,88,89,184,185)   MV_F(ari1,90,91,186,187) \
        MV_F(aii0,124,125,188,189) MV_F(aii1,126,127,190,191) \
        MV_F(ari0,92,93,188,189)   MV_F(ari1,94,95,190,191) \
        : [arr0]"=&v"(arr0), [arr1]"=&v"(arr1), [air0]"=&v"(air0), [air1]"=&v"(air1), \
          [aii0]"=&v"(aii0), [aii1]"=&v"(aii1), [ari0]"=&v"(ari0), [ari1]"=&v"(ari1) \
        : "{v[64:79]}"(wrA), "{v[80:95]}"(wrB), "{v[96:111]}"(wiA), "{v[112:127]}"(wiB), \
          "{v[128:143]}"(axr0), "{v[144:159]}"(axr1), "{v[160:175]}"(axi0), "{v[176:191]}"(axi1))

#define MATVEC_B() \
    asm volatile( \
        MV_M(arr0,64,65,192,193)   MV_M(arr1,66,67,194,195) \
        MV_M(air0,96,97,192,193)   MV_M(air1,98,99,194,195) \
        MV_F(arr0,68,69,196,197)   MV_F(arr1,70,71,198,199) \
        MV_F(air0,100,101,196,197) MV_F(air1,102,103,198,199) \
        MV_F(arr0,72,73,200,201)   MV_F(arr1,74,75,202,203) \
        MV_F(air0,104,105,200,201) MV_F(air1,106,107,202,203) \
        MV_F(arr0,76,77,204,205)   MV_F(arr1,78,79,206,207) \
        MV_F(air0,108,109,204,205) MV_F(air1,110,111,206,207) \
        MV_F(arr0,80,81,208,209)   MV_F(arr1,82,83,210,211) \
        MV_F(air0,112,113,208,209) MV_F(air1,114,115,210,211) \
        MV_F(arr0,84,85,212,213)   MV_F(arr1,86,87,214,215) \
        MV_F(air0,116,117,212,213) MV_F(air1,118,119,214,215) \
        MV_F(arr0,88,89,216,217)   MV_F(arr1,90,91,218,219) \
        MV_F(air0,120,121,216,217) MV_F(air1,122,123,218,219) \
        MV_F(arr0,92,93,220,221)   MV_F(arr1,94,95,222,223) \
        MV_F(air0,124,125,220,221) MV_F(air1,126,127,222,223) \
        MV_M(aii0,96,97,224,225)   MV_M(aii1,98,99,226,227) \
        MV_M(ari0,64,65,224,225)   MV_M(ari1,66,67,226,227) \
        MV_F(aii0,100,101,228,229) MV_F(aii1,102,103,230,231) \
        MV_F(ari0,68,69,228,229)   MV_F(ari1,70,71,230,231) \
        MV_F(aii0,104,105,232,233) MV_F(aii1,106,107,234,235) \
        MV_F(ari0,72,73,232,233)   MV_F(ari1,74,75,234,235) \
        MV_F(aii0,108,109,236,237) MV_F(aii1,110,111,238,239) \
        MV_F(ari0,76,77,236,237)   MV_F(ari1,78,79,238,239) \
        MV_F(aii0,112,113,240,241) MV_F(aii1,114,115,242,243) \
        MV_F(ari0,80,81,240,241)   MV_F(ari1,82,83,242,243) \
        MV_F(aii0,116,117,244,245) MV_F(aii1,118,119,246,247) \
        MV_F(ari0,84,85,244,245)   MV_F(ari1,86,87,246,247) \
        MV_F(aii0,120,121,248,249) MV_F(aii1,122,123,250,251) \
        MV_F(ari0,88,89,248,249)   MV_F(ari1,90,91,250,251) \
        MV_F(aii0,124,125,252,253) MV_F(aii1,126,127,254,255) \
        MV_F(ari0,92,93,252,253)   MV_F(ari1,94,95,254,255) \
        : [arr0]"=&v"(arr0), [arr1]"=&v"(arr1), [air0]"=&v"(air0), [air1]"=&v"(air1), \
          [aii0]"=&v"(aii0), [aii1]"=&v"(aii1), [ari0]"=&v"(ari0), [ari1]"=&v"(ari1) \
        : "{v[64:79]}"(wrA), "{v[80:95]}"(wrB), "{v[96:111]}"(wiA), "{v[112:127]}"(wiB), \
          "{v[192:207]}"(bxr0), "{v[208:223]}"(bxr1), "{v[224:239]}"(bxi0), "{v[240:255]}"(bxi1))

#define WUPD_A(G2, M12) \
    asm volatile( \
        WU(64,65,128,129,s0)    WU(66,67,130,131,s1) \
        WU(68,69,132,133,s0)    WU(70,71,134,135,s1) \
        WU(72,73,136,137,s0)    WU(74,75,138,139,s1) \
        WU(76,77,140,141,s0)    WU(78,79,142,143,s1) \
        WU(80,81,144,145,s0)    WU(82,83,146,147,s1) \
        WU(84,85,148,149,s0)    WU(86,87,150,151,s1) \
        WU(88,89,152,153,s0)    WU(90,91,154,155,s1) \
        WU(92,93,156,157,s0)    WU(94,95,158,159,s1) \
        WU(96,97,160,161,s0)    WU(98,99,162,163,s1) \
        WU(100,101,164,165,s0)  WU(102,103,166,167,s1) \
        WU(104,105,168,169,s0)  WU(106,107,170,171,s1) \
        WU(108,109,172,173,s0)  WU(110,111,174,175,s1) \
        WU(112,113,176,177,s0)  WU(114,115,178,179,s1) \
        WU(116,117,180,181,s0)  WU(118,119,182,183,s1) \
        WU(120,121,184,185,s0)  WU(122,123,186,187,s1) \
        WU(124,125,188,189,s0)  WU(126,127,190,191,s1) \
        : [s0]"=&v"(wuscr0), [s1]"=&v"(wuscr1), \
          "+{v[64:79]}"(wrA), "+{v[80:95]}"(wrB), "+{v[96:111]}"(wiA), "+{v[112:127]}"(wiB) \
        : [g2]"v"(G2), [m1]"v"(M12), \
          "{v[128:143]}"(axr0), "{v[144:159]}"(axr1), "{v[160:175]}"(axi0), "{v[176:191]}"(axi1))

#define WUPD_B(G2, M12) \
    asm volatile( \
        WU(64,65,192,193,s0)    WU(66,67,194,195,s1) \
        WU(68,69,196,197,s0)    WU(70,71,198,199,s1) \
        WU(72,73,200,201,s0)    WU(74,75,202,203,s1) \
        WU(76,77,204,205,s0)    WU(78,79,206,207,s1) \
        WU(80,81,208,209,s0)    WU(82,83,210,211,s1) \
        WU(84,85,212,213,s0)    WU(86,87,214,215,s1) \
        WU(88,89,216,217,s0)    WU(90,91,218,219,s1) \
        WU(92,93,220,221,s0)    WU(94,95,222,223,s1) \
        WU(96,97,224,225,s0)    WU(98,99,226,227,s1) \
        WU(100,101,228,229,s0)  WU(102,103,230,231,s1) \
        WU(104,105,232,233,s0)  WU(106,107,234,235,s1) \
        WU(108,109,236,237,s0)  WU(110,111,238,239,s1) \
        WU(112,113,240,241,s0)  WU(114,115,242,243,s1) \
        WU(116,117,244,245,s0)  WU(118,119,246,247,s1) \
        WU(120,121,248,249,s0)  WU(122,123,250,251,s1) \
        WU(124,125,252,253,s0)  WU(126,127,254,255,s1) \
        : [s0]"=&v"(wuscr0), [s1]"=&v"(wuscr1), \
          "+{v[64:79]}"(wrA), "+{v[80:95]}"(wrB), "+{v[96:111]}"(wiA), "+{v[112:127]}"(wiB) \
        : [g2]"v"(G2), [m1]"v"(M12), \
          "{v[192:207]}"(bxr0), "{v[208:223]}"(bxr1), "{v[224:239]}"(bxi0), "{v[240:255]}"(bxi1))

    // ---- prologue: x(0)->A, x(1)->B, tgt(0)/tgt(1); P_0 = W0 @ x(0) ----
    LOADX_A(Xr, Xi);
    LOADX_B(Xr + DD, Xi + DD);
    SL1(tgA, Tg); SL1(tgB, Tg + 1);
    asm volatile("s_waitcnt vmcnt(16)" ::: "memory");   // bufA landed
    float Pr, Pi;
    {
        v2f arr0, arr1, aii0, aii1, ari0, ari1, air0, air1;
        MATVEC_A();
        const float hArr = (arr0.x + arr0.y) + (arr1.x + arr1.y);
        const float hAii = (aii0.x + aii0.y) + (aii1.x + aii1.y);
        const float hAri = (ari0.x + ari0.y) + (ari1.x + ari1.y);
        const float hAir = (air0.x + air0.y) + (air1.x + air1.y);
        Pr = hArr - hAii;
        Pi = hAri + hAir;
    }
    asm volatile("s_waitcnt lgkmcnt(0)" : "+s"(tgA), "+s"(tgB) :: "memory");

    // Iter T: publish Y(T) (P in hand) -> barrier -> out(T) -> feedback(T)
    // -> WU (W becomes W_used(T+1)) -> P_{T+1} = W @ x(T+1) (bit-identical
    // matvec, just computed one iteration early) -> loads x(T+2) -> stores.
#define BODY(T, CUR, OTH, TGT)                                                   \
    {                                                                            \
        /* re-tie TGT: its s_load was drained by the PREVIOUS barrier; the   */  \
        /* tie stops the compiler hoisting uses above that barrier.          */  \
        asm volatile("" : "+s"(TGT));                                            \
        const float tgt = TGT;                                                   \
        /* 1: trig for step T (beta = beta(T), carried) */                       \
        const float gamma = __expf(-0.5f * beta);                                \
        const float dtl = gamma * F_DT;                                          \
        lt += dtl;                                                               \
        const float theta = fmaf(F_OMEGA, lt, phi);                              \
        float rev = theta * F_INV_TWO_PI; rev -= floorf(rev);                    \
        const float s = __builtin_amdgcn_sinf(rev);                              \
        const float c = __builtin_amdgcn_cosf(rev);                              \
        const float a_sA = 1.0f - __expf(-2.0f * F_DT * (gamma + 1e-6f));        \
        /* 2: Y(T) from carried P (== R6's zr,zi) and publish */                 \
        const float Y = fmaxf(fmaf(Pr, c, Pi * s), 0.0f);                        \
        float v = wave_reduce_to_lane63(Y * c);                                  \
        if (lane == 63) sP[(((T) & 1) << 3) + wid] = v;                          \
        /* 3: pre-barrier tail */                                                \
        const float inv_t = 1.0f / (fabsf(tgt) + 0.01f);                         \
        const float yy = Y * Y;                                                  \
        const float g = 0.05f * Y * dtl;                                         \
        phi += (2.0f / (float)NN) * (-tgt * s) * dtl;                            \
        phi = phi - F_TWO_PI * floorf(phi * F_INV_TWO_PI);                       \
        /* 4: barrier (drains lane63 sP write + any pending tgt s_load) */       \
        barrier_lgkm();                                                          \
        /* 5: out(T) */                                                          \
        const unsigned lsp = (unsigned)(unsigned long long)                      \
            (lds_f*)&sP[((T) & 1) << 3];                                         \
        v4f p0, p1;                                                              \
        DSR128(p0, lsp, 0); DSR128(p1, lsp, 16);                                 \
        asm volatile("s_waitcnt lgkmcnt(0)" : "+v"(p0), "+v"(p1) :: "memory");   \
        const float out = ((p0.x + p0.y) + (p0.z + p0.w)) +                      \
                          ((p1.x + p1.y) + (p1.z + p1.w));                       \
        /* 6: feedback(T) — identical op order to R6 */                          \
        const float raw = fabsf(tgt - out);                                      \
        err = 0.99f * err + 0.01f * raw;                                         \
        const float rel = err * inv_t;                                           \
        const float btg = 3.5f * __expf(-5.0f * rel);                            \
        const float a_s = (btg > beta) ? a_sA : a_sB;                            \
        float bnew = beta + a_s * (btg - beta);                                  \
        bnew = fminf(fmaxf(bnew, 0.005f), 5.0f);                                 \
        const float m1 = 1.0f - (bnew * yy) * dtl;                               \
        beta = bnew;                                                             \
        /* 7: WU on CUR buffer (x(T)) — same mul->fma pairs as R6 */             \
        const v2f g2 = {g, g}; const v2f m12 = {m1, m1};                         \
        WUPD_##CUR(g2, m12);                                                     \
        /* 8: P_{T+1} = W @ x(T+1) (OTH buffer; loads had a full step) */        \
        asm volatile("s_waitcnt vmcnt(3)" ::: "memory");                         \
        {                                                                        \
            v2f arr0, arr1, aii0, aii1, ari0, ari1, air0, air1;                  \
            MATVEC_##OTH();                                                      \
            const float hArr = (arr0.x + arr0.y) + (arr1.x + arr1.y);            \
            const float hAii = (aii0.x + aii0.y) + (aii1.x + aii1.y);            \
            const float hAri = (ari0.x + ari0.y) + (ari1.x + ari1.y);            \
            const float hAir = (air0.x + air0.y) + (air1.x + air1.y);            \
            Pr = hArr - hAii;                                                    \
            Pi = hAri + hAir;                                                    \
        }                                                                        \
        /* 9: refill CUR with x(T+2); tgt(T+2) */                                \
        {                                                                        \
            const int tf = ((T) + 2 < TT) ? (T) + 2 : (TT - 1);                  \
            LOADX_##CUR(Xr + (size_t)tf * DD, Xi + (size_t)tf * DD);             \
            SL1(TGT, Tg + tf);                                                   \
        }                                                                        \
        /* 10: outputs (fire-and-forget; 3 VMEM stores after the 16 loads) */    \
        gammas[(T) * NN + n] = gamma;                                            \
        betas[(T) * NN + n] = bnew;                                              \
        if (lane == 63) outs[T] = out;                                           \
    }

    for (int t = 0; t < TT; t += 2) {
        BODY(t, A, B, tgA);
        BODY(t + 1, B, A, tgB);
    }

    // Drain: final LOADX/SL1 land in pinned/unused regs; don't exit with
    // outstanding memory ops.
    asm volatile("s_waitcnt vmcnt(0) lgkmcnt(0)" ::: "memory");
}

extern "C" void kernel_launch(void* const* d_in, const int* in_sizes, int n_in,
                              void* d_out, int out_size, void* d_ws, size_t ws_size,
                              hipStream_t stream) {
    const float* Xr    = (const float*)d_in[0];   // [T, D]
    const float* Xi    = (const float*)d_in[1];   // [T, D]
    const float* Tg    = (const float*)d_in[2];   // [T]
    const float* W0r   = (const float*)d_in[3];   // [N, D]
    const float* W0i   = (const float*)d_in[4];   // [N, D]
    const float* Phi0  = (const float*)d_in[5];   // [N]
    const float* Beta0 = (const float*)d_in[6];   // [N]

    float* outs   = (float*)d_out;                // [T]
    float* betas  = outs + TT;                    // [T, N]
    float* gammas = betas + (size_t)TT * NN;      // [T, N]

    deerskin<<<1, NN, 0, stream>>>(Xr, Xi, Tg, W0r, W0i, Phi0, Beta0,
                                   outs, betas, gammas);
}

// Round 12
// 7899.051 us; speedup vs baseline: 1.5355x; 1.5355x over previous
//
#include <hip/hip_runtime.h>

#define NN 512
#define DD 32
#define TT 8192

typedef float v4f __attribute__((ext_vector_type(4)));
typedef float v2f __attribute__((ext_vector_type(2)));
typedef float v16f __attribute__((ext_vector_type(16)));
typedef __attribute__((address_space(3))) float lds_f;

constexpr float F_OMEGA = 10.0f;
constexpr float F_DT = 1e-3f;
constexpr float F_TWO_PI = 6.28318530717958647692f;
constexpr float F_INV_TWO_PI = 0.15915494309189533577f;

__device__ __forceinline__ void barrier_lgkm() {
    asm volatile("s_waitcnt lgkmcnt(0)\n\ts_barrier" ::: "memory");
}

#define DSR128(dst, addr, off) \
    asm volatile("ds_read_b128 %0, %1 offset:" #off : "=v"(dst) : "v"(addr))

#define SL16(dst, ptr, off) \
    asm volatile("s_load_dwordx16 %0, %1, " #off : "=s"(dst) : "s"(ptr))
#define SL1(dst, ptr) \
    asm volatile("s_load_dword %0, %1, 0x0" : "=s"(dst) : "s"(ptr))

#define DPP_ADD(x, ctrl, rmask)                                                 \
    {                                                                           \
        int _t = __builtin_amdgcn_update_dpp(0, __float_as_int(x),              \
                                             (ctrl), (rmask), 0xf, true);       \
        (x) += __int_as_float(_t);                                              \
    }

__device__ __forceinline__ float wave_reduce_to_lane63(float x) {
    DPP_ADD(x, 0xB1, 0xf);   // + xor1
    DPP_ADD(x, 0x4E, 0xf);   // + xor2
    DPP_ADD(x, 0x141, 0xf);  // + xor4
    DPP_ADD(x, 0x140, 0xf);  // + xor8
    DPP_ADD(x, 0x142, 0xa);  // row_bcast15
    DPP_ADD(x, 0x143, 0xc);  // row_bcast31
    return x;                // lane 63 = full wave sum
}

// Expand two v16f (SGPR-resident) into 16 v2f pair views (SGPR subregs).
#define MKP(dst, lo, hi)                                                        \
    dst[0]  = __builtin_shufflevector(lo, lo, 0, 1);                            \
    dst[1]  = __builtin_shufflevector(lo, lo, 2, 3);                            \
    dst[2]  = __builtin_shufflevector(lo, lo, 4, 5);                            \
    dst[3]  = __builtin_shufflevector(lo, lo, 6, 7);                            \
    dst[4]  = __builtin_shufflevector(lo, lo, 8, 9);                            \
    dst[5]  = __builtin_shufflevector(lo, lo, 10, 11);                          \
    dst[6]  = __builtin_shufflevector(lo, lo, 12, 13);                          \
    dst[7]  = __builtin_shufflevector(lo, lo, 14, 15);                          \
    dst[8]  = __builtin_shufflevector(hi, hi, 0, 1);                            \
    dst[9]  = __builtin_shufflevector(hi, hi, 2, 3);                            \
    dst[10] = __builtin_shufflevector(hi, hi, 4, 5);                            \
    dst[11] = __builtin_shufflevector(hi, hi, 6, 7);                            \
    dst[12] = __builtin_shufflevector(hi, hi, 8, 9);                            \
    dst[13] = __builtin_shufflevector(hi, hi, 10, 11);                          \
    dst[14] = __builtin_shufflevector(hi, hi, 12, 13);                          \
    dst[15] = __builtin_shufflevector(hi, hi, 14, 15);

// x pair operand lists for the asm blobs (16 "s" inputs each).
#define XIN(x) \
    "s"(x[0]), "s"(x[1]), "s"(x[2]), "s"(x[3]), "s"(x[4]), "s"(x[5]), \
    "s"(x[6]), "s"(x[7]), "s"(x[8]), "s"(x[9]), "s"(x[10]), "s"(x[11]), \
    "s"(x[12]), "s"(x[13]), "s"(x[14]), "s"(x[15])

__global__ __launch_bounds__(512, 2) void deerskin(
    const float* __restrict__ Xr, const float* __restrict__ Xi,
    const float* __restrict__ Tg,
    const float* __restrict__ W0r, const float* __restrict__ W0i,
    const float* __restrict__ Phi0, const float* __restrict__ Beta0,
    float* __restrict__ outs, float* __restrict__ betas, float* __restrict__ gammas)
{
    // Only remaining LDS: 16-float double-buffered partial array.
    __shared__ __align__(16) float sP[16];

    const int n = threadIdx.x;
    const int lane = n & 63;
    const int wid = n >> 6;

    // ---- W state PINNED to physical ArchVGPRs v[64:127] (R6) ----
    v16f wrA, wrB, wiA, wiB;
    {
        const v16f* r = (const v16f*)(W0r + n * DD);
        const v16f* i = (const v16f*)(W0i + n * DD);
        v16f t0 = r[0], t1 = r[1], t2 = i[0], t3 = i[1];
        asm volatile("" : "={v[64:79]}"(wrA) : "0"(t0));
        asm volatile("" : "={v[80:95]}"(wrB) : "0"(t1));
        asm volatile("" : "={v[96:111]}"(wiA) : "0"(t2));
        asm volatile("" : "={v[112:127]}"(wiB) : "0"(t3));
    }

    // ---- tw staging PINNED to v[128:191] ----
    // R10 lesson: all per-step work lives between consecutive publishes; the
    // only lever is FILLING the post-barrier stall window (sP ds_read ~120cy
    // + feedback ~100cy, where both waves per SIMD have nothing to issue).
    // tw = g*x(t) is feedback-INDEPENDENT (g known pre-barrier), so its 32
    // pk ops (256cy issue per SIMD) are placed INSIDE that window. The W
    // update then shrinks to 32 feedback-dependent fmas. Same mul->fma per
    // pair, same operands, same order as R6 -> bit-identical FP.
    v16f twA, twB, twC, twD;
    {
        v16f z = {0,0,0,0,0,0,0,0,0,0,0,0,0,0,0,0};
        asm volatile("" : "={v[128:143]}"(twA) : "0"(z));
        asm volatile("" : "={v[144:159]}"(twB) : "0"(z));
        asm volatile("" : "={v[160:175]}"(twC) : "0"(z));
        asm volatile("" : "={v[176:191]}"(twD) : "0"(z));
    }

    float phi = Phi0[n];
    float beta = Beta0[n];
    float lt = 0.0f;
    float err = 0.0f;

    // Loop-carried SGPR-resident x(t).
    v16f sxr0, sxr1, sxi0, sxi1;
    float stgt;

    // ---- prologue: issue x(0) scalar loads (drained by the t=0 tie-wait).
    SL16(sxr0, Xr, 0x0); SL16(sxr1, Xr, 0x40);
    SL16(sxi0, Xi, 0x0); SL16(sxi1, Xi, 0x40);
    SL1(stgt, Tg);

    for (int t = 0; t < TT; ++t) {
        // ---- 1. x-independent precompute (beta-dependent arm) ----
        const float gamma = __expf(-0.5f * beta);
        const float dtl = gamma * F_DT;
        lt += dtl;
        const float theta = fmaf(F_OMEGA, lt, phi);
        float rev = theta * F_INV_TWO_PI;
        rev -= floorf(rev);
        const float s = __builtin_amdgcn_sinf(rev);
        const float c = __builtin_amdgcn_cosf(rev);
        const float a_sA = 1.0f - __expf(-2.0f * F_DT * (gamma + 1e-6f));
        const float a_sB = 1.0f - __expf(-F_DT / 0.03f);

        // ---- 2. tie-wait for x(t) ----
        asm volatile("s_waitcnt lgkmcnt(0)"
            : "+s"(sxr0), "+s"(sxr1), "+s"(sxi0), "+s"(sxi1), "+s"(stgt)
            :: "memory");
        const float tgt = stgt;

        v2f xr_[16], xi_[16];
        MKP(xr_, sxr0, sxr1);
        MKP(xi_, sxi0, sxi1);

        // ---- 3. Z = W @ x: two blobs, pinned-W pairs referenced directly.
        // Chain order per accumulator identical to R5/R6 -> bit-identical FP.
        v2f arr0, arr1, aii0, aii1, ari0, ari1, air0, air1;
        asm volatile(
            "v_pk_mul_f32 %0, v[64:65], %8\n\t"
            "v_pk_mul_f32 %1, v[66:67], %9\n\t"
            "v_pk_mul_f32 %2, v[96:97], %8\n\t"
            "v_pk_mul_f32 %3, v[98:99], %9\n\t"
            "v_pk_fma_f32 %0, v[68:69], %10, %0\n\t"
            "v_pk_fma_f32 %1, v[70:71], %11, %1\n\t"
            "v_pk_fma_f32 %2, v[100:101], %10, %2\n\t"
            "v_pk_fma_f32 %3, v[102:103], %11, %3\n\t"
            "v_pk_fma_f32 %0, v[72:73], %12, %0\n\t"
            "v_pk_fma_f32 %1, v[74:75], %13, %1\n\t"
            "v_pk_fma_f32 %2, v[104:105], %12, %2\n\t"
            "v_pk_fma_f32 %3, v[106:107], %13, %3\n\t"
            "v_pk_fma_f32 %0, v[76:77], %14, %0\n\t"
            "v_pk_fma_f32 %1, v[78:79], %15, %1\n\t"
            "v_pk_fma_f32 %2, v[108:109], %14, %2\n\t"
            "v_pk_fma_f32 %3, v[110:111], %15, %3\n\t"
            "v_pk_fma_f32 %0, v[80:81], %16, %0\n\t"
            "v_pk_fma_f32 %1, v[82:83], %17, %1\n\t"
            "v_pk_fma_f32 %2, v[112:113], %16, %2\n\t"
            "v_pk_fma_f32 %3, v[114:115], %17, %3\n\t"
            "v_pk_fma_f32 %0, v[84:85], %18, %0\n\t"
            "v_pk_fma_f32 %1, v[86:87], %19, %1\n\t"
            "v_pk_fma_f32 %2, v[116:117], %18, %2\n\t"
            "v_pk_fma_f32 %3, v[118:119], %19, %3\n\t"
            "v_pk_fma_f32 %0, v[88:89], %20, %0\n\t"
            "v_pk_fma_f32 %1, v[90:91], %21, %1\n\t"
            "v_pk_fma_f32 %2, v[120:121], %20, %2\n\t"
            "v_pk_fma_f32 %3, v[122:123], %21, %3\n\t"
            "v_pk_fma_f32 %0, v[92:93], %22, %0\n\t"
            "v_pk_fma_f32 %1, v[94:95], %23, %1\n\t"
            "v_pk_fma_f32 %2, v[124:125], %22, %2\n\t"
            "v_pk_fma_f32 %3, v[126:127], %23, %3"
            : "=&v"(arr0), "=&v"(arr1), "=&v"(air0), "=&v"(air1)
            : "{v[64:79]}"(wrA), "{v[80:95]}"(wrB),
              "{v[96:111]}"(wiA), "{v[112:127]}"(wiB), XIN(xr_));
        asm volatile(
            "v_pk_mul_f32 %0, v[96:97], %8\n\t"
            "v_pk_mul_f32 %1, v[98:99], %9\n\t"
            "v_pk_mul_f32 %2, v[64:65], %8\n\t"
            "v_pk_mul_f32 %3, v[66:67], %9\n\t"
            "v_pk_fma_f32 %0, v[100:101], %10, %0\n\t"
            "v_pk_fma_f32 %1, v[102:103], %11, %1\n\t"
            "v_pk_fma_f32 %2, v[68:69], %10, %2\n\t"
            "v_pk_fma_f32 %3, v[70:71], %11, %3\n\t"
            "v_pk_fma_f32 %0, v[104:105], %12, %0\n\t"
            "v_pk_fma_f32 %1, v[106:107], %13, %1\n\t"
            "v_pk_fma_f32 %2, v[72:73], %12, %2\n\t"
            "v_pk_fma_f32 %3, v[74:75], %13, %3\n\t"
            "v_pk_fma_f32 %0, v[108:109], %14, %0\n\t"
            "v_pk_fma_f32 %1, v[110:111], %15, %1\n\t"
            "v_pk_fma_f32 %2, v[76:77], %14, %2\n\t"
            "v_pk_fma_f32 %3, v[78:79], %15, %3\n\t"
            "v_pk_fma_f32 %0, v[112:113], %16, %0\n\t"
            "v_pk_fma_f32 %1, v[114:115], %17, %1\n\t"
            "v_pk_fma_f32 %2, v[80:81], %16, %2\n\t"
            "v_pk_fma_f32 %3, v[82:83], %17, %3\n\t"
            "v_pk_fma_f32 %0, v[116:117], %18, %0\n\t"
            "v_pk_fma_f32 %1, v[118:119], %19, %1\n\t"
            "v_pk_fma_f32 %2, v[84:85], %18, %2\n\t"
            "v_pk_fma_f32 %3, v[86:87], %19, %3\n\t"
            "v_pk_fma_f32 %0, v[120:121], %20, %0\n\t"
            "v_pk_fma_f32 %1, v[122:123], %21, %1\n\t"
            "v_pk_fma_f32 %2, v[88:89], %20, %2\n\t"
            "v_pk_fma_f32 %3, v[90:91], %21, %3\n\t"
            "v_pk_fma_f32 %0, v[124:125], %22, %0\n\t"
            "v_pk_fma_f32 %1, v[126:127], %23, %1\n\t"
            "v_pk_fma_f32 %2, v[92:93], %22, %2\n\t"
            "v_pk_fma_f32 %3, v[94:95], %23, %3"
            : "=&v"(aii0), "=&v"(aii1), "=&v"(ari0), "=&v"(ari1)
            : "{v[64:79]}"(wrA), "{v[80:95]}"(wrB),
              "{v[96:111]}"(wiA), "{v[112:127]}"(wiB), XIN(xi_));

        const float hArr = (arr0.x + arr0.y) + (arr1.x + arr1.y);
        const float hAii = (aii0.x + aii0.y) + (aii1.x + aii1.y);
        const float hAri = (ari0.x + ari0.y) + (ari1.x + ari1.y);
        const float hAir = (air0.x + air0.y) + (air1.x + air1.y);
        const float zr = hArr - hAii;
        const float zi = hAri + hAir;

        // Y = |Z| * relu(cos(theta - angle(Z))) == relu(zr*cos + zi*sin)
        const float Y = fmaxf(fmaf(zr, c, zi * s), 0.0f);

        // ---- 4. reduce 512 -> 1: DPP wave sum, 8 partials via LDS ----
        float v = wave_reduce_to_lane63(Y * c);
        if (lane == 63) sP[((t & 1) << 3) + wid] = v;

        // ---- 5. pre-barrier tail ----
        const float inv_t = 1.0f / (fabsf(tgt) + 0.01f);
        const float yy = Y * Y;
        const float g = 0.05f * Y * dtl;
        const v2f g2 = {g, g};
        phi += (2.0f / (float)NN) * (-tgt * s) * dtl;
        phi = phi - F_TWO_PI * floorf(phi * F_INV_TWO_PI);
        gammas[t * NN + n] = gamma;   // gamma from OLD beta, per reference

        // ---- 6. barrier (drains only lane63's sP ds_write) ----
        barrier_lgkm();

        // ---- 7. sP reads ISSUED, then tw = g*x(t) fills the read latency
        // and the feedback window (the R11 change): 32 pk of feedback-
        // independent issue inside the formerly-dead stall window.
        const unsigned lsp =
            (unsigned)(unsigned long long)(lds_f*)&sP[(t & 1) << 3];
        v4f p0, p1;
        DSR128(p0, lsp, 0); DSR128(p1, lsp, 16);
        asm volatile(
            "v_pk_mul_f32 v[128:129], %[g2], %[x0]\n\t"
            "v_pk_mul_f32 v[130:131], %[g2], %[x1]\n\t"
            "v_pk_mul_f32 v[132:133], %[g2], %[x2]\n\t"
            "v_pk_mul_f32 v[134:135], %[g2], %[x3]\n\t"
            "v_pk_mul_f32 v[136:137], %[g2], %[x4]\n\t"
            "v_pk_mul_f32 v[138:139], %[g2], %[x5]\n\t"
            "v_pk_mul_f32 v[140:141], %[g2], %[x6]\n\t"
            "v_pk_mul_f32 v[142:143], %[g2], %[x7]\n\t"
            "v_pk_mul_f32 v[144:145], %[g2], %[x8]\n\t"
            "v_pk_mul_f32 v[146:147], %[g2], %[x9]\n\t"
            "v_pk_mul_f32 v[148:149], %[g2], %[x10]\n\t"
            "v_pk_mul_f32 v[150:151], %[g2], %[x11]\n\t"
            "v_pk_mul_f32 v[152:153], %[g2], %[x12]\n\t"
            "v_pk_mul_f32 v[154:155], %[g2], %[x13]\n\t"
            "v_pk_mul_f32 v[156:157], %[g2], %[x14]\n\t"
            "v_pk_mul_f32 v[158:159], %[g2], %[x15]"
            : "+{v[128:143]}"(twA), "+{v[144:159]}"(twB)
            : [g2]"v"(g2),
              [x0]"s"(xr_[0]), [x1]"s"(xr_[1]), [x2]"s"(xr_[2]), [x3]"s"(xr_[3]),
              [x4]"s"(xr_[4]), [x5]"s"(xr_[5]), [x6]"s"(xr_[6]), [x7]"s"(xr_[7]),
              [x8]"s"(xr_[8]), [x9]"s"(xr_[9]), [x10]"s"(xr_[10]), [x11]"s"(xr_[11]),
              [x12]"s"(xr_[12]), [x13]"s"(xr_[13]), [x14]"s"(xr_[14]), [x15]"s"(xr_[15]));
        asm volatile(
            "v_pk_mul_f32 v[160:161], %[g2], %[x0]\n\t"
            "v_pk_mul_f32 v[162:163], %[g2], %[x1]\n\t"
            "v_pk_mul_f32 v[164:165], %[g2], %[x2]\n\t"
            "v_pk_mul_f32 v[166:167], %[g2], %[x3]\n\t"
            "v_pk_mul_f32 v[168:169], %[g2], %[x4]\n\t"
            "v_pk_mul_f32 v[170:171], %[g2], %[x5]\n\t"
            "v_pk_mul_f32 v[172:173], %[g2], %[x6]\n\t"
            "v_pk_mul_f32 v[174:175], %[g2], %[x7]\n\t"
            "v_pk_mul_f32 v[176:177], %[g2], %[x8]\n\t"
            "v_pk_mul_f32 v[178:179], %[g2], %[x9]\n\t"
            "v_pk_mul_f32 v[180:181], %[g2], %[x10]\n\t"
            "v_pk_mul_f32 v[182:183], %[g2], %[x11]\n\t"
            "v_pk_mul_f32 v[184:185], %[g2], %[x12]\n\t"
            "v_pk_mul_f32 v[186:187], %[g2], %[x13]\n\t"
            "v_pk_mul_f32 v[188:189], %[g2], %[x14]\n\t"
            "v_pk_mul_f32 v[190:191], %[g2], %[x15]"
            : "+{v[160:175]}"(twC), "+{v[176:191]}"(twD)
            : [g2]"v"(g2),
              [x0]"s"(xi_[0]), [x1]"s"(xi_[1]), [x2]"s"(xi_[2]), [x3]"s"(xi_[3]),
              [x4]"s"(xi_[4]), [x5]"s"(xi_[5]), [x6]"s"(xi_[6]), [x7]"s"(xi_[7]),
              [x8]"s"(xi_[8]), [x9]"s"(xi_[9]), [x10]"s"(xi_[10]), [x11]"s"(xi_[11]),
              [x12]"s"(xi_[12]), [x13]"s"(xi_[13]), [x14]"s"(xi_[14]), [x15]"s"(xi_[15]));

        asm volatile("s_waitcnt lgkmcnt(0)" : "+v"(p0), "+v"(p1) :: "memory");

        // ---- 8. out + short scalar feedback chain ----
        const float out = ((p0.x + p0.y) + (p0.z + p0.w)) +
                          ((p1.x + p1.y) + (p1.z + p1.w));
        const float raw = fabsf(tgt - out);
        err = 0.99f * err + 0.01f * raw;
        const float rel = err * inv_t;
        const float btg = 3.5f * __expf(-5.0f * rel);
        const float a_s = (btg > beta) ? a_sA : a_sB;
        float bnew = beta + a_s * (btg - beta);
        bnew = fminf(fmaxf(bnew, 0.005f), 5.0f);

        // ---- 9. W = W*m1 + tw: only 32 feedback-dependent fmas remain ----
        const float k = (bnew * yy) * dtl;
        const float m1 = 1.0f - k;
        const v2f m12 = {m1, m1};
        asm volatile(
            "v_pk_fma_f32 v[64:65], v[64:65], %[m1], v[128:129]\n\t"
            "v_pk_fma_f32 v[66:67], v[66:67], %[m1], v[130:131]\n\t"
            "v_pk_fma_f32 v[68:69], v[68:69], %[m1], v[132:133]\n\t"
            "v_pk_fma_f32 v[70:71], v[70:71], %[m1], v[134:135]\n\t"
            "v_pk_fma_f32 v[72:73], v[72:73], %[m1], v[136:137]\n\t"
            "v_pk_fma_f32 v[74:75], v[74:75], %[m1], v[138:139]\n\t"
            "v_pk_fma_f32 v[76:77], v[76:77], %[m1], v[140:141]\n\t"
            "v_pk_fma_f32 v[78:79], v[78:79], %[m1], v[142:143]\n\t"
            "v_pk_fma_f32 v[80:81], v[80:81], %[m1], v[144:145]\n\t"
            "v_pk_fma_f32 v[82:83], v[82:83], %[m1], v[146:147]\n\t"
            "v_pk_fma_f32 v[84:85], v[84:85], %[m1], v[148:149]\n\t"
            "v_pk_fma_f32 v[86:87], v[86:87], %[m1], v[150:151]\n\t"
            "v_pk_fma_f32 v[88:89], v[88:89], %[m1], v[152:153]\n\t"
            "v_pk_fma_f32 v[90:91], v[90:91], %[m1], v[154:155]\n\t"
            "v_pk_fma_f32 v[92:93], v[92:93], %[m1], v[156:157]\n\t"
            "v_pk_fma_f32 v[94:95], v[94:95], %[m1], v[158:159]"
            : "+{v[64:79]}"(wrA), "+{v[80:95]}"(wrB)
            : [m1]"v"(m12), "{v[128:143]}"(twA), "{v[144:159]}"(twB));
        asm volatile(
            "v_pk_fma_f32 v[96:97], v[96:97], %[m1], v[160:161]\n\t"
            "v_pk_fma_f32 v[98:99], v[98:99], %[m1], v[162:163]\n\t"
            "v_pk_fma_f32 v[100:101], v[100:101], %[m1], v[164:165]\n\t"
            "v_pk_fma_f32 v[102:103], v[102:103], %[m1], v[166:167]\n\t"
            "v_pk_fma_f32 v[104:105], v[104:105], %[m1], v[168:169]\n\t"
            "v_pk_fma_f32 v[106:107], v[106:107], %[m1], v[170:171]\n\t"
            "v_pk_fma_f32 v[108:109], v[108:109], %[m1], v[172:173]\n\t"
            "v_pk_fma_f32 v[110:111], v[110:111], %[m1], v[174:175]\n\t"
            "v_pk_fma_f32 v[112:113], v[112:113], %[m1], v[176:177]\n\t"
            "v_pk_fma_f32 v[114:115], v[114:115], %[m1], v[178:179]\n\t"
            "v_pk_fma_f32 v[116:117], v[116:117], %[m1], v[180:181]\n\t"
            "v_pk_fma_f32 v[118:119], v[118:119], %[m1], v[182:183]\n\t"
            "v_pk_fma_f32 v[120:121], v[120:121], %[m1], v[184:185]\n\t"
            "v_pk_fma_f32 v[122:123], v[122:123], %[m1], v[186:187]\n\t"
            "v_pk_fma_f32 v[124:125], v[124:125], %[m1], v[188:189]\n\t"
            "v_pk_fma_f32 v[126:127], v[126:127], %[m1], v[190:191]"
            : "+{v[96:111]}"(wiA), "+{v[112:127]}"(wiB)
            : [m1]"v"(m12), "{v[160:175]}"(twC), "{v[176:191]}"(twD));

        // ---- 10. prefetch x(t+1) (x(t) dead after tw) ----
        {
            const int tn = (t + 1 < TT) ? (t + 1) : (TT - 1);
            const float* xrp = Xr + (size_t)tn * DD;
            const float* xip = Xi + (size_t)tn * DD;
            const float* tgp = Tg + tn;
            SL16(sxr0, xrp, 0x0); SL16(sxr1, xrp, 0x40);
            SL16(sxi0, xip, 0x0); SL16(sxi1, xip, 0x40);
            SL1(stgt, tgp);
        }

        // ---- 11. outputs (fire-and-forget; no vmcnt waits anywhere) ----
        betas[t * NN + n] = bnew;
        if (lane == 63) outs[t] = out;
        beta = bnew;
    }
}

extern "C" void kernel_launch(void* const* d_in, const int* in_sizes, int n_in,
                              void* d_out, int out_size, void* d_ws, size_t ws_size,
                              hipStream_t stream) {
    const float* Xr    = (const float*)d_in[0];   // [T, D]
    const float* Xi    = (const float*)d_in[1];   // [T, D]
    const float* Tg    = (const float*)d_in[2];   // [T]
    const float* W0r   = (const float*)d_in[3];   // [N, D]
    const float* W0i   = (const float*)d_in[4];   // [N, D]
    const float* Phi0  = (const float*)d_in[5];   // [N]
    const float* Beta0 = (const float*)d_in[6];   // [N]

    float* outs   = (float*)d_out;                // [T]
    float* betas  = outs + TT;                    // [T, N]
    float* gammas = betas + (size_t)TT * NN;      // [T, N]

    deerskin<<<1, NN, 0, stream>>>(Xr, Xi, Tg, W0r, W0i, Phi0, Beta0,
                                   outs, betas, gammas);
}